// Round 9
// baseline (336.488 us; speedup 1.0000x reference)
//
#include <hip/hip_runtime.h>
#include <math.h>

// ---- problem constants ----
#define NB 2
#define NS 2048
#define NE 768
#define NF 3072
#define NHEAD 12
#define NTOK 4096   // B*S
#define LDW 1344    // padded inner dim for Aext/Wc (21*64)

typedef __bf16 bf16;
typedef __bf16 bf16x4 __attribute__((ext_vector_type(4)));
typedef __bf16 bf16x8 __attribute__((ext_vector_type(8)));
typedef float  f32x4  __attribute__((ext_vector_type(4)));

__device__ __forceinline__ f32x4 mfma_bf16(bf16x8 a, bf16x8 b, f32x4 c) {
  return __builtin_amdgcn_mfma_f32_16x16x32_bf16(a, b, c, 0, 0, 0);
}

__device__ __forceinline__ float fast_exp2(float x) {
#if __has_builtin(__builtin_amdgcn_exp2f)
  return __builtin_amdgcn_exp2f(x);
#else
  return exp2f(x);
#endif
}

// async global->LDS, 16B per lane. LDS dest must be wave-uniform base + lane*16.
__device__ __forceinline__ void glds16(const void* g, void* l) {
  __builtin_amdgcn_global_load_lds((const __attribute__((address_space(1))) void*)g,
                                   (__attribute__((address_space(3))) void*)l,
                                   16, 0, 0);
}

// XCD-band swizzle (gridDim.y % 8 == 0 at all call sites).
__device__ __forceinline__ void swz_xy(int& bx, int& by) {
  int gx = gridDim.x;
  int i = by*gx + bx;
  int xcd = i & 7, s = i >> 3;
  int bands = gridDim.y >> 3;
  by = xcd*bands + s / gx;
  bx = s % gx;
}

// ---------------- weight prep: fp32 -> bf16 (+ reshapes/concat) ----------------
__global__ void prep_kernel(const float* __restrict__ in_proj, const float* __restrict__ out_proj,
                            const float* __restrict__ ffn1_w, const float* __restrict__ ffn1_b,
                            const float* __restrict__ ffn2_w,
                            const float* __restrict__ hA_w1, const float* __restrict__ hA_b1,
                            const float* __restrict__ hA_w2, const float* __restrict__ hA_b2,
                            const float* __restrict__ hB_w1, const float* __restrict__ hB_b1,
                            const float* __restrict__ hB_w2,
                            const float* __restrict__ task,
                            bf16* __restrict__ Wqkv, bf16* __restrict__ Wo, bf16* __restrict__ W2,
                            bf16* __restrict__ W1ab, float* __restrict__ b1ab,
                            bf16* __restrict__ WBp, bf16* __restrict__ Wc,
                            bf16* __restrict__ task_bf)
{
  __shared__ float tb[64*130];
  int stride = gridDim.x * blockDim.x;
  int t0 = blockIdx.x * blockDim.x + threadIdx.x;
  // q rows (first 768) pre-scaled by (1/sqrt(HD)) * log2(e) so flash can use exp2
  const float QS = 0.125f * 1.44269504088896f;
  for (int i = t0; i < 2304*768; i += stride)
    Wqkv[i] = (bf16)(i < 768*768 ? in_proj[i] * QS : in_proj[i]);
  for (int i = t0; i < 768*768;  i += stride) Wo[i]   = (bf16)out_proj[i];
  for (int i = t0; i < 768*3072; i += stride) W2[i]   = (bf16)ffn2_w[i];
  for (int i = t0; i < 256*128;  i += stride)
    W1ab[i] = (bf16)(i < 128*128 ? hA_w1[i] : hB_w1[i - 128*128]);
  for (int i = t0; i < 256; i += stride) b1ab[i] = (i < 128) ? hA_b1[i] : hB_b1[i-128];
  for (int i = t0; i < NTOK*128; i += stride) task_bf[i] = (bf16)task[i];

  // WBp[n=(r*128+h)][e] = hB_w2[r*768+e][h] via 64x128 LDS transpose
  for (int j0 = blockIdx.x*64; j0 < 3072; j0 += gridDim.x*64) {
    __syncthreads();
    for (int i = threadIdx.x; i < 64*128; i += 256) {
      int jr = i >> 7, hh = i & 127;
      tb[jr*130 + hh] = hB_w2[(long)(j0 + jr)*128 + hh];
    }
    __syncthreads();
    int r = j0 / 768, e0 = j0 % 768;
    for (int i = threadIdx.x; i < 128*64; i += 256) {
      int hh = i >> 6, jr = i & 63;
      WBp[(long)(r*128 + hh)*768 + e0 + jr] = (bf16)tb[jr*130 + hh];
    }
  }

  // Wc[f][0:768]=ffn1_w ; [768+h*4+r]=hA_w2[(f*4+r)][h] ; [1280+r]=hA_b2[f*4+r] ;
  // [1284]=ffn1_b[f] ; [1285:1344]=0.  (stride LDW=1344)
  for (int f = blockIdx.x; f < 3072; f += gridDim.x) {
    const float* hrow = hA_w2 + (long)f*512;
    bf16* wrow = Wc + (long)f*LDW;
    for (int c = threadIdx.x; c < 768; c += 256) wrow[c] = (bf16)ffn1_w[(long)f*768 + c];
    for (int i = threadIdx.x; i < 512; i += 256) {
      int r = i >> 7, h = i & 127;
      wrow[768 + h*4 + r] = (bf16)hrow[i];
    }
    if (threadIdx.x < 4)        wrow[1280 + threadIdx.x] = (bf16)hA_b2[f*4 + threadIdx.x];
    else if (threadIdx.x == 4)  wrow[1284] = (bf16)ffn1_b[f];
    else if (threadIdx.x < 64)  wrow[1280 + threadIdx.x] = (bf16)0.f;
  }
}

// ---------------- RMSNorm (fp32 in -> bf16 out, arbitrary out row stride) ------
__global__ __launch_bounds__(256) void rmsnorm_k(const float* __restrict__ x,
                                                 const float* __restrict__ w,
                                                 bf16* __restrict__ out, int ld_out)
{
  __shared__ float red[4];
  long t = blockIdx.x;
  const float* xr = x + t*NE;
  float ss = 0.f;
  #pragma unroll
  for (int i = 0; i < 3; i++) { float v = xr[threadIdx.x + i*256]; ss += v*v; }
  #pragma unroll
  for (int d = 1; d < 64; d <<= 1) ss += __shfl_xor(ss, d, 64);
  if ((threadIdx.x & 63) == 0) red[threadIdx.x >> 6] = ss;
  __syncthreads();
  float tot = red[0] + red[1] + red[2] + red[3];
  float scale = rsqrtf(tot * (1.f/768.f) + 1.1920928955078125e-07f);
  #pragma unroll
  for (int i = 0; i < 3; i++) {
    int idx = threadIdx.x + i*256;
    out[t*ld_out + idx] = (bf16)(xr[idx] * scale * w[idx]);
  }
}

// ---------------- 64x64-tile GEMM, BK=64, XOR-swizzled LDS --------------------
// 4 waves of 32Mx32N; conflict-free ds_read_b128; high block count for latency
// overlap (R8-verified). K % 64 == 0.
template<typename OutT, bool RELU, bool BIAS, bool RES>
__global__ __launch_bounds__(256) void gemm64(const bf16* __restrict__ A,
                                              const bf16* __restrict__ Bm,
                                              OutT* __restrict__ C,
                                              const float* __restrict__ bias,
                                              const float* __restrict__ res,
                                              int K, int lda, int ldb, int ldc)
{
  __shared__ bf16 As[2][64*64];
  __shared__ bf16 Bs[2][64*64];
  const int tid = threadIdx.x;
  int bx = blockIdx.x, by = blockIdx.y;
  swz_xy(bx, by);
  const int m0 = by * 64, n0 = bx * 64;
  const int w = tid >> 6, lane = tid & 63;
  const int quad = lane >> 4, l16 = lane & 15;
  const int wy = w >> 1, wx = w & 1;     // wave tile: 32M x 32N
  const int sw = l16 & 7;                // fragment-read swizzle

  f32x4 acc[2][2];
  #pragma unroll
  for (int i = 0; i < 2; i++)
    #pragma unroll
    for (int j = 0; j < 2; j++) acc[i][j] = (f32x4){0.f,0.f,0.f,0.f};

  const int c0 = tid, c1 = tid + 256;
  const int r0 = c0 >> 3, g0 = ((c0 & 7) ^ (r0 & 7)) * 8;
  const int r1 = c1 >> 3, g1 = ((c1 & 7) ^ (r1 & 7)) * 8;
  const bf16* pA0 = A  + (long)(m0 + r0)*lda + g0;
  const bf16* pA1 = A  + (long)(m0 + r1)*lda + g1;
  const bf16* pB0 = Bm + (long)(n0 + r0)*ldb + g0;
  const bf16* pB1 = Bm + (long)(n0 + r1)*ldb + g1;
  auto stage = [&](int buf) {
    glds16(pA0, (void*)(&As[buf][c0*8]));
    glds16(pA1, (void*)(&As[buf][c1*8]));
    glds16(pB0, (void*)(&Bs[buf][c0*8]));
    glds16(pB1, (void*)(&Bs[buf][c1*8]));
    pA0 += 64; pA1 += 64; pB0 += 64; pB1 += 64;
  };

  stage(0);
  __builtin_amdgcn_s_waitcnt(0);
  __syncthreads();

  const int nsteps = K >> 6;
  for (int s = 0; s < nsteps; ++s) {
    const int cur = s & 1;
    if (s + 1 < nsteps) stage(cur ^ 1);

    bf16x8 af[2][2], bfr[2][2];
    #pragma unroll
    for (int mi = 0; mi < 2; ++mi)
      #pragma unroll
      for (int kb = 0; kb < 2; ++kb)
        af[mi][kb] = *(const bf16x8*)(&As[cur][(wy*32 + mi*16 + l16)*64 + (((kb*4 + quad) ^ sw))*8]);
    #pragma unroll
    for (int ni = 0; ni < 2; ++ni)
      #pragma unroll
      for (int kb = 0; kb < 2; ++kb)
        bfr[ni][kb] = *(const bf16x8*)(&Bs[cur][(wx*32 + ni*16 + l16)*64 + (((kb*4 + quad) ^ sw))*8]);
    #pragma unroll
    for (int kb = 0; kb < 2; ++kb)
      #pragma unroll
      for (int mi = 0; mi < 2; ++mi)
        #pragma unroll
        for (int ni = 0; ni < 2; ++ni)
          acc[mi][ni] = mfma_bf16(af[mi][kb], bfr[ni][kb], acc[mi][ni]);

    __builtin_amdgcn_s_waitcnt(0);
    __syncthreads();
  }

  #pragma unroll
  for (int mi = 0; mi < 2; ++mi)
    #pragma unroll
    for (int ni = 0; ni < 2; ++ni) {
      int col = n0 + wx*32 + ni*16 + l16;
      #pragma unroll
      for (int r = 0; r < 4; ++r) {
        long row = m0 + wy*32 + mi*16 + quad*4 + r;
        float v = acc[mi][ni][r];
        if (BIAS) v += bias[col];
        if (RES)  v += res[row*ldc + col];
        if (RELU) v = v > 0.f ? v : 0.f;
        C[row*ldc + col] = (OutT)v;
      }
    }
}

// ---- QKV GEMM: 64x64-tile variant with split epilogue:
// cols<1536 -> Qkv[t][2304]; V block -> Vt[bh][d][s] directly.
__global__ __launch_bounds__(256) void gemm_qkv64(const bf16* __restrict__ A,
                                                  const bf16* __restrict__ Bm,
                                                  bf16* __restrict__ Qkv,
                                                  bf16* __restrict__ Vt)
{
  __shared__ bf16 As[2][64*64];
  __shared__ bf16 Bs[2][64*64];
  const int tid = threadIdx.x;
  int bx = blockIdx.x, by = blockIdx.y;
  swz_xy(bx, by);
  const int m0 = by * 64, n0 = bx * 64;
  const int w = tid >> 6, lane = tid & 63;
  const int quad = lane >> 4, l16 = lane & 15;
  const int wy = w >> 1, wx = w & 1;
  const int sw = l16 & 7;

  f32x4 acc[2][2];
  #pragma unroll
  for (int i = 0; i < 2; i++)
    #pragma unroll
    for (int j = 0; j < 2; j++) acc[i][j] = (f32x4){0.f,0.f,0.f,0.f};

  const int c0 = tid, c1 = tid + 256;
  const int r0 = c0 >> 3, g0 = ((c0 & 7) ^ (r0 & 7)) * 8;
  const int r1 = c1 >> 3, g1 = ((c1 & 7) ^ (r1 & 7)) * 8;
  const bf16* pA0 = A  + (long)(m0 + r0)*768 + g0;
  const bf16* pA1 = A  + (long)(m0 + r1)*768 + g1;
  const bf16* pB0 = Bm + (long)(n0 + r0)*768 + g0;
  const bf16* pB1 = Bm + (long)(n0 + r1)*768 + g1;
  auto stage = [&](int buf) {
    glds16(pA0, (void*)(&As[buf][c0*8]));
    glds16(pA1, (void*)(&As[buf][c1*8]));
    glds16(pB0, (void*)(&Bs[buf][c0*8]));
    glds16(pB1, (void*)(&Bs[buf][c1*8]));
    pA0 += 64; pA1 += 64; pB0 += 64; pB1 += 64;
  };

  stage(0);
  __builtin_amdgcn_s_waitcnt(0);
  __syncthreads();

  for (int s = 0; s < 12; ++s) {           // K=768
    const int cur = s & 1;
    if (s + 1 < 12) stage(cur ^ 1);

    bf16x8 af[2][2], bfr[2][2];
    #pragma unroll
    for (int mi = 0; mi < 2; ++mi)
      #pragma unroll
      for (int kb = 0; kb < 2; ++kb)
        af[mi][kb] = *(const bf16x8*)(&As[cur][(wy*32 + mi*16 + l16)*64 + (((kb*4 + quad) ^ sw))*8]);
    #pragma unroll
    for (int ni = 0; ni < 2; ++ni)
      #pragma unroll
      for (int kb = 0; kb < 2; ++kb)
        bfr[ni][kb] = *(const bf16x8*)(&Bs[cur][(wx*32 + ni*16 + l16)*64 + (((kb*4 + quad) ^ sw))*8]);
    #pragma unroll
    for (int kb = 0; kb < 2; ++kb)
      #pragma unroll
      for (int mi = 0; mi < 2; ++mi)
        #pragma unroll
        for (int ni = 0; ni < 2; ++ni)
          acc[mi][ni] = mfma_bf16(af[mi][kb], bfr[ni][kb], acc[mi][ni]);

    __builtin_amdgcn_s_waitcnt(0);
    __syncthreads();
  }

  const int bb = m0 >> 11;                  // batch (tile is 2048-aligned)
  #pragma unroll
  for (int mi = 0; mi < 2; ++mi)
    #pragma unroll
    for (int ni = 0; ni < 2; ++ni) {
      int col = n0 + wx*32 + ni*16 + l16;
      #pragma unroll
      for (int r = 0; r < 4; ++r) {
        long row = m0 + wy*32 + mi*16 + quad*4 + r;
        bf16 v = (bf16)acc[mi][ni][r];
        if (col < 1536) {
          Qkv[row*2304 + col] = v;
        } else {
          int vc = col - 1536;
          int hh = vc >> 6, d = vc & 63;
          long srow = row & (NS-1);
          Vt[((long)(bb*NHEAD + hh)*64 + d)*NS + srow] = v;
        }
      }
    }
}

// ---------------- flash attention v4 --------------------------------------------
// S^T = mfma(K, Q); P stays in registers as PV A-fragments (R6-verified mapping).
// lsum computed by an extra ones-column MFMA (o5) — lands in C-layout, so the
// epilogue needs no cross-lane reduction. KV loop unrolled x2 so `cur` is a
// literal: all LDS read addresses are loop-invariant (buffer parity folds into
// the ds_read offset immediate).
__global__ __launch_bounds__(256) void flash_attn(const bf16* __restrict__ Qkv,
                                                  const bf16* __restrict__ Vt,
                                                  bf16* __restrict__ Ctx)
{
  __shared__ bf16 Ks[2][64*64];
  __shared__ bf16 Vs[2][64*64];

  const int tid = threadIdx.x;
  const int w = tid >> 6, lane = tid & 63;
  const int quad = lane >> 4, l16 = lane & 15;
  const int bh = blockIdx.y;
  const int b = bh / NHEAD, h = bh % NHEAD;
  const int q0 = blockIdx.x * 64;
  const long tq = (long)(b*NS + q0 + w*16 + l16);

  bf16x8 qf[2];   // q pre-scaled by 0.125*log2e via Wqkv
  qf[0] = *(const bf16x8*)(Qkv + tq*2304 + h*64 + quad*8);
  qf[1] = *(const bf16x8*)(Qkv + tq*2304 + h*64 + 32 + quad*8);

  bf16x8 ones;
  #pragma unroll
  for (int j = 0; j < 8; ++j) ones[j] = (bf16)1.0f;

  f32x4 o[4];
  f32x4 o5 = (f32x4){0.f,0.f,0.f,0.f};
  #pragma unroll
  for (int i = 0; i < 4; i++) o[i] = (f32x4){0.f,0.f,0.f,0.f};

  const int c0 = tid, c1 = tid + 256;
  const int r0 = c0 >> 3, g0 = ((c0 & 7) ^ (r0 & 7)) * 8;
  const int r1 = c1 >> 3, g1 = ((c1 & 7) ^ (r1 & 7)) * 8;
  const bf16* kp0 = Qkv + (long)(b*NS + r0)*2304 + 768 + h*64 + g0;
  const bf16* kp1 = Qkv + (long)(b*NS + r1)*2304 + 768 + h*64 + g1;
  const bf16* vp0 = Vt + ((long)bh*64 + r0)*NS + g0;
  const bf16* vp1 = Vt + ((long)bh*64 + r1)*NS + g1;

  auto stage = [&](int buf) {
    glds16(kp0, (void*)(&Ks[buf][c0*8]));
    glds16(kp1, (void*)(&Ks[buf][c1*8]));
    glds16(vp0, (void*)(&Vs[buf][c0*8]));
    glds16(vp1, (void*)(&Vs[buf][c1*8]));
    kp0 += 64*2304; kp1 += 64*2304; vp0 += 64; vp1 += 64;
  };

  auto body = [&](int cur) {   // cur is a literal at every call site
    // S^T = K Q^T : s[nt] holds kv = nt*16 + quad*4 + r, q = l16
    f32x4 s[4];
    #pragma unroll
    for (int nt = 0; nt < 4; ++nt) {
      s[nt] = (f32x4){0.f,0.f,0.f,0.f};
      #pragma unroll
      for (int kb = 0; kb < 2; ++kb) {
        bf16x8 kf = *(const bf16x8*)(&Ks[cur][(nt*16 + l16)*64 + (((kb*4 + quad) ^ (l16 & 7)))*8]);
        s[nt] = mfma_bf16(kf, qf[kb], s[nt]);   // A=K, B=Q -> S^T
      }
    }
    // P = exp2(S^T) in registers; pack straight into PV A-fragments
    bf16x8 pf[2];
    #pragma unroll
    for (int nt = 0; nt < 4; ++nt)
      #pragma unroll
      for (int r = 0; r < 4; ++r)
        pf[nt >> 1][(nt & 1)*4 + r] = (bf16)fast_exp2(s[nt][r]);
    // PV + row-sum column
    #pragma unroll
    for (int ntp = 0; ntp < 2; ++ntp) {
      #pragma unroll
      for (int dt = 0; dt < 4; ++dt) {
        int row = dt*16 + l16;                       // d
        int cA = ntp*4 + (quad >> 1);
        int base = row*64 + (quad & 1)*4;
        bf16x4 va = *(const bf16x4*)(&Vs[cur][base + ((cA       ^ (row & 7)) << 3)]);
        bf16x4 vb = *(const bf16x4*)(&Vs[cur][base + (((cA + 2) ^ (row & 7)) << 3)]);
        bf16x8 vf = {va[0],va[1],va[2],va[3], vb[0],vb[1],vb[2],vb[3]};
        o[dt] = mfma_bf16(pf[ntp], vf, o[dt]);
      }
      o5 = mfma_bf16(pf[ntp], ones, o5);           // lsum in C-layout
    }
  };

  stage(0);
  __builtin_amdgcn_s_waitcnt(0);
  __syncthreads();

  for (int t = 0; t < NS/64; t += 2) {
    stage(1);                        // t+1 < 32 always (t <= 30)
    body(0);
    __builtin_amdgcn_s_waitcnt(0);
    __syncthreads();
    if (t + 2 < NS/64) stage(0);
    body(1);
    __builtin_amdgcn_s_waitcnt(0);
    __syncthreads();
  }

  #pragma unroll
  for (int r = 0; r < 4; ++r) {
    float inv = 1.f / o5[r];
    long trow = (long)(b*NS + q0 + w*16 + quad*4 + r);
    #pragma unroll
    for (int dt = 0; dt < 4; ++dt)
      Ctx[trow*NE + h*64 + dt*16 + l16] = (bf16)(o[dt][r] * inv);
  }
}

// ---------------- per-token: inter + build g/ones/zeros cols of Aext -----------
// 4 waves/block, one token per wave. Aext stride LDW; cols 1285..1343 zeroed.
__global__ __launch_bounds__(256) void build_g(const bf16* __restrict__ HAB,
                                               const float* __restrict__ P,
                                               const float* __restrict__ hB_b2,
                                               bf16* __restrict__ Aext)
{
  long t = blockIdx.x*4 + (threadIdx.x >> 6);
  int lane = threadIdx.x & 63;
  const bf16* xr = Aext + t*LDW;             // cols 0..767 = xn2
  float acc[4] = {0.f, 0.f, 0.f, 0.f};
  for (int i = lane; i < 768; i += 64) {
    float xv = (float)xr[i];
    #pragma unroll
    for (int r = 0; r < 4; ++r) acc[r] += xv * hB_b2[r*768 + i];
  }
  const bf16* hB = HAB + t*256 + 128;
  const float* Pr = P + t*512;
  #pragma unroll
  for (int k = 0; k < 2; ++k) {
    int h = lane + k*64;
    float hv = (float)hB[h];
    #pragma unroll
    for (int r = 0; r < 4; ++r) acc[r] += hv * Pr[r*128 + h];
  }
  #pragma unroll
  for (int r = 0; r < 4; ++r)
    #pragma unroll
    for (int d = 1; d < 64; d <<= 1) acc[r] += __shfl_xor(acc[r], d, 64);

  bf16* grow = Aext + t*LDW + 768;
  const bf16* hA = HAB + t*256;
  #pragma unroll
  for (int j = 0; j < 8; ++j) {
    int idx = lane*8 + j;                    // 0..511
    int h = idx >> 2, r = idx & 3;
    grow[idx] = (bf16)((float)hA[h] * acc[r]);
  }
  if (lane < 4)       Aext[t*LDW + 1280 + lane] = (bf16)acc[lane];
  else if (lane == 4) Aext[t*LDW + 1284] = (bf16)1.0f;
  else                Aext[t*LDW + 1280 + lane] = (bf16)0.f;   // 1285..1343
}

// ---------------- host launcher ----------------
extern "C" void kernel_launch(void* const* d_in, const int* in_sizes, int n_in,
                              void* d_out, int out_size, void* d_ws, size_t ws_size,
                              hipStream_t stream)
{
  const float* src      = (const float*)d_in[0];
  const float* task     = (const float*)d_in[1];
  const float* norm1_w  = (const float*)d_in[2];
  const float* norm2_w  = (const float*)d_in[3];
  const float* in_proj  = (const float*)d_in[4];
  const float* out_proj = (const float*)d_in[5];
  const float* ffn1_w   = (const float*)d_in[6];
  const float* ffn1_b   = (const float*)d_in[7];
  const float* ffn2_w   = (const float*)d_in[8];
  const float* ffn2_b   = (const float*)d_in[9];
  const float* hA_w1    = (const float*)d_in[10];
  const float* hA_b1    = (const float*)d_in[11];
  const float* hA_w2    = (const float*)d_in[12];
  const float* hA_b2    = (const float*)d_in[13];
  const float* hB_w1    = (const float*)d_in[14];
  const float* hB_b1    = (const float*)d_in[15];
  const float* hB_w2    = (const float*)d_in[16];
  const float* hB_b2    = (const float*)d_in[17];
  float* out = (float*)d_out;

  char* ws = (char*)d_ws;
  size_t off = 0;
  auto alloc = [&](size_t bytes) { size_t o = off; off += (bytes + 255) & ~(size_t)255; return o; };
  bf16*  Wqkv   = (bf16*)(ws + alloc(2304*768*2));
  bf16*  Wo     = (bf16*)(ws + alloc(768*768*2));
  bf16*  W2     = (bf16*)(ws + alloc(768*3072*2));
  bf16*  W1ab   = (bf16*)(ws + alloc(256*128*2));
  float* b1ab   = (float*)(ws + alloc(256*4));
  bf16*  WBp    = (bf16*)(ws + alloc(512*768*2));
  bf16*  Wc     = (bf16*)(ws + alloc((size_t)3072*LDW*2));
  bf16*  taskbf = (bf16*)(ws + alloc((size_t)NTOK*128*2));
  bf16*  XC     = (bf16*)(ws + alloc((size_t)NTOK*768*2));    // Xn1, then Ctx
  char*  QKVH   = ws + alloc(25165824);                        // Qkv(18874368)+Vt(6291456) / Hbuf
  bf16*  Qkv    = (bf16*)QKVH;
  bf16*  Vt     = (bf16*)(QKVH + 18874368);
  bf16*  Hbuf   = (bf16*)QKVH;
  float* Src2   = (float*)(ws + alloc((size_t)NTOK*768*4));
  bf16*  Aext   = (bf16*)(ws + alloc((size_t)NTOK*LDW*2));
  bf16*  HAB    = (bf16*)(ws + alloc((size_t)NTOK*256*2));
  float* P      = (float*)(ws + alloc((size_t)NTOK*512*4));

  // K0: weight prep / casts
  prep_kernel<<<dim3(1280), 256, 0, stream>>>(in_proj, out_proj, ffn1_w, ffn1_b, ffn2_w,
      hA_w1, hA_b1, hA_w2, hA_b2, hB_w1, hB_b1, hB_w2, task,
      Wqkv, Wo, W2, W1ab, b1ab, WBp, Wc, taskbf);
  // K1: x1 = rmsnorm(src, norm1_w) -> bf16
  rmsnorm_k<<<dim3(NTOK), 256, 0, stream>>>(src, norm1_w, XC, 768);
  // K2: qkv = x1 @ in_proj^T ; V block written directly to Vt
  gemm_qkv64<<<dim3(36,64), 256, 0, stream>>>(XC, Wqkv, Qkv, Vt);
  // K4: flash attention -> Ctx (reuses XC)
  flash_attn<<<dim3(32,24), 256, 0, stream>>>(Qkv, Vt, XC);
  // K5: src2 = src + ctx @ out_proj^T
  gemm64<float,false,false,true><<<dim3(12,64), 256, 0, stream>>>(XC, Wo, Src2, nullptr, src, 768, 768, 768, 768);
  // K6: xn2 = rmsnorm(src2, norm2_w) -> Aext cols 0..767 (stride LDW)
  rmsnorm_k<<<dim3(NTOK), 256, 0, stream>>>(Src2, norm2_w, Aext, LDW);
  // K7: HAB = relu(task @ W1ab^T + b1ab)
  gemm64<bf16,true,true,false><<<dim3(4,64), 256, 0, stream>>>(taskbf, W1ab, HAB, b1ab, nullptr, 128, 128, 128, 256);
  // K8: P = xn2 @ WBp^T
  gemm64<float,false,false,false><<<dim3(8,64), 256, 0, stream>>>(Aext, WBp, P, nullptr, nullptr, 768, LDW, 768, 512);
  // K9: inter + g -> Aext cols 768..1343
  build_g<<<dim3(NTOK/4), 256, 0, stream>>>(HAB, P, hB_b2, Aext);
  // K10: H = relu(Aext @ Wc^T)  (64-tile path, K padded to 1344)
  gemm64<bf16,true,false,false><<<dim3(48,64), 256, 0, stream>>>(Aext, Wc, Hbuf, nullptr, nullptr, LDW, LDW, LDW, 3072);
  // K11: out = src2 + H @ ffn2_w^T + ffn2_b
  gemm64<float,false,true,true><<<dim3(12,64), 256, 0, stream>>>(Hbuf, W2, out, ffn2_b, Src2, 3072, 3072, 3072, 768);
}

// Round 10
// 327.770 us; speedup vs baseline: 1.0266x; 1.0266x over previous
//
#include <hip/hip_runtime.h>
#include <math.h>

// ---- problem constants ----
#define NB 2
#define NS 2048
#define NE 768
#define NF 3072
#define NHEAD 12
#define NTOK 4096   // B*S
#define LDW 1344    // padded inner dim for Aext/Wc (21*64)

typedef __bf16 bf16;
typedef __bf16 bf16x4 __attribute__((ext_vector_type(4)));
typedef __bf16 bf16x8 __attribute__((ext_vector_type(8)));
typedef float  f32x4  __attribute__((ext_vector_type(4)));

__device__ __forceinline__ f32x4 mfma_bf16(bf16x8 a, bf16x8 b, f32x4 c) {
  return __builtin_amdgcn_mfma_f32_16x16x32_bf16(a, b, c, 0, 0, 0);
}

__device__ __forceinline__ float fast_exp2(float x) {
#if __has_builtin(__builtin_amdgcn_exp2f)
  return __builtin_amdgcn_exp2f(x);
#else
  return exp2f(x);
#endif
}

// async global->LDS, 16B per lane. LDS dest must be wave-uniform base + lane*16.
__device__ __forceinline__ void glds16(const void* g, void* l) {
  __builtin_amdgcn_global_load_lds((const __attribute__((address_space(1))) void*)g,
                                   (__attribute__((address_space(3))) void*)l,
                                   16, 0, 0);
}

// XCD-band swizzle (gridDim.y % 8 == 0 at all call sites).
__device__ __forceinline__ void swz_xy(int& bx, int& by) {
  int gx = gridDim.x;
  int i = by*gx + bx;
  int xcd = i & 7, s = i >> 3;
  int bands = gridDim.y >> 3;
  by = xcd*bands + s / gx;
  bx = s % gx;
}

// ---------------- weight prep: fp32 -> bf16 (+ reshapes/concat) ----------------
__global__ void prep_kernel(const float* __restrict__ in_proj, const float* __restrict__ out_proj,
                            const float* __restrict__ ffn1_w, const float* __restrict__ ffn1_b,
                            const float* __restrict__ ffn2_w,
                            const float* __restrict__ hA_w1, const float* __restrict__ hA_b1,
                            const float* __restrict__ hA_w2, const float* __restrict__ hA_b2,
                            const float* __restrict__ hB_w1, const float* __restrict__ hB_b1,
                            const float* __restrict__ hB_w2,
                            const float* __restrict__ task,
                            bf16* __restrict__ Wqkv, bf16* __restrict__ Wo, bf16* __restrict__ W2,
                            bf16* __restrict__ W1ab, float* __restrict__ b1ab,
                            bf16* __restrict__ WBp, bf16* __restrict__ Wc,
                            bf16* __restrict__ task_bf)
{
  __shared__ float tb[64*130];
  int stride = gridDim.x * blockDim.x;
  int t0 = blockIdx.x * blockDim.x + threadIdx.x;
  // q rows (first 768) pre-scaled by (1/sqrt(HD)) * log2(e) so flash can use exp2
  const float QS = 0.125f * 1.44269504088896f;
  for (int i = t0; i < 2304*768; i += stride)
    Wqkv[i] = (bf16)(i < 768*768 ? in_proj[i] * QS : in_proj[i]);
  for (int i = t0; i < 768*768;  i += stride) Wo[i]   = (bf16)out_proj[i];
  for (int i = t0; i < 768*3072; i += stride) W2[i]   = (bf16)ffn2_w[i];
  for (int i = t0; i < 256*128;  i += stride)
    W1ab[i] = (bf16)(i < 128*128 ? hA_w1[i] : hB_w1[i - 128*128]);
  for (int i = t0; i < 256; i += stride) b1ab[i] = (i < 128) ? hA_b1[i] : hB_b1[i-128];
  for (int i = t0; i < NTOK*128; i += stride) task_bf[i] = (bf16)task[i];

  // WBp[n=(r*128+h)][e] = hB_w2[r*768+e][h] via 64x128 LDS transpose
  for (int j0 = blockIdx.x*64; j0 < 3072; j0 += gridDim.x*64) {
    __syncthreads();
    for (int i = threadIdx.x; i < 64*128; i += 256) {
      int jr = i >> 7, hh = i & 127;
      tb[jr*130 + hh] = hB_w2[(long)(j0 + jr)*128 + hh];
    }
    __syncthreads();
    int r = j0 / 768, e0 = j0 % 768;
    for (int i = threadIdx.x; i < 128*64; i += 256) {
      int hh = i >> 6, jr = i & 63;
      WBp[(long)(r*128 + hh)*768 + e0 + jr] = (bf16)tb[jr*130 + hh];
    }
  }

  // Wc[f][0:768]=ffn1_w ; [768+h*4+r]=hA_w2[(f*4+r)][h] ; [1280+r]=hA_b2[f*4+r] ;
  // [1284]=ffn1_b[f] ; [1285:1344]=0.  (stride LDW=1344)
  for (int f = blockIdx.x; f < 3072; f += gridDim.x) {
    const float* hrow = hA_w2 + (long)f*512;
    bf16* wrow = Wc + (long)f*LDW;
    for (int c = threadIdx.x; c < 768; c += 256) wrow[c] = (bf16)ffn1_w[(long)f*768 + c];
    for (int i = threadIdx.x; i < 512; i += 256) {
      int r = i >> 7, h = i & 127;
      wrow[768 + h*4 + r] = (bf16)hrow[i];
    }
    if (threadIdx.x < 4)        wrow[1280 + threadIdx.x] = (bf16)hA_b2[f*4 + threadIdx.x];
    else if (threadIdx.x == 4)  wrow[1284] = (bf16)ffn1_b[f];
    else if (threadIdx.x < 64)  wrow[1280 + threadIdx.x] = (bf16)0.f;
  }
}

// ---------------- RMSNorm (fp32 in -> bf16 out, arbitrary out row stride) ------
__global__ __launch_bounds__(256) void rmsnorm_k(const float* __restrict__ x,
                                                 const float* __restrict__ w,
                                                 bf16* __restrict__ out, int ld_out)
{
  __shared__ float red[4];
  long t = blockIdx.x;
  const float* xr = x + t*NE;
  float ss = 0.f;
  #pragma unroll
  for (int i = 0; i < 3; i++) { float v = xr[threadIdx.x + i*256]; ss += v*v; }
  #pragma unroll
  for (int d = 1; d < 64; d <<= 1) ss += __shfl_xor(ss, d, 64);
  if ((threadIdx.x & 63) == 0) red[threadIdx.x >> 6] = ss;
  __syncthreads();
  float tot = red[0] + red[1] + red[2] + red[3];
  float scale = rsqrtf(tot * (1.f/768.f) + 1.1920928955078125e-07f);
  #pragma unroll
  for (int i = 0; i < 3; i++) {
    int idx = threadIdx.x + i*256;
    out[t*ld_out + idx] = (bf16)(xr[idx] * scale * w[idx]);
  }
}

// ------- 128x128 BK=32 GEMM, conflict-free superrow-swizzled LDS ---------------
// LDS layout per tile: element (row r, chunk c in 0..3 of 8 elems) lives at
//   R = r>>1 ; cc = (r&1)*4 + c ; slot j = cc ^ (R&7) ; offset = R*128B + j*16B.
// A full wave64 ds_read_b128 fragment touches each 16B slot of 8 superrows
// exactly once -> zero bank conflicts. Staging applies the inverse permutation
// on the GLOBAL address (lane-linear LDS dest as glds16 requires); coalescing
// stays 64B-segmented. 128-tile keeps HBM traffic at half the 64-tile's.
template<typename OutT, bool RELU, bool BIAS, bool RES>
__global__ __launch_bounds__(256) void gemm_bt_sw(const bf16* __restrict__ A,
                                                  const bf16* __restrict__ Bm,
                                                  OutT* __restrict__ C,
                                                  const float* __restrict__ bias,
                                                  const float* __restrict__ res,
                                                  int K, int lda, int ldb, int ldc)
{
  __shared__ bf16 As[2][128*32];
  __shared__ bf16 Bs[2][128*32];
  const int tid = threadIdx.x;
  int bx = blockIdx.x, by = blockIdx.y;
  swz_xy(bx, by);
  const int m0 = by * 128;
  const int n0 = bx * 128;
  const int w = tid >> 6, lane = tid & 63;
  const int quad = lane >> 4, l16 = lane & 15;
  const int wy = w >> 1, wx = w & 1;

  f32x4 acc[4][4];
  #pragma unroll
  for (int i = 0; i < 4; i++)
    #pragma unroll
    for (int j = 0; j < 4; j++) acc[i][j] = (f32x4){0.f,0.f,0.f,0.f};

  // staging source permutation: LDS linear index i -> (R=i>>3, j=i&7),
  // cc = j ^ (R&7), r = 2R + (cc>>2), chunk = cc&3.
  const int i0 = tid, i1 = tid + 256;
  const int R0 = i0 >> 3, cc0 = (i0 & 7) ^ (R0 & 7), r0 = 2*R0 + (cc0 >> 2), ch0 = (cc0 & 3) * 8;
  const int R1 = i1 >> 3, cc1 = (i1 & 7) ^ (R1 & 7), r1 = 2*R1 + (cc1 >> 2), ch1 = (cc1 & 3) * 8;
  const bf16* pA0 = A  + (long)(m0 + r0)*lda + ch0;
  const bf16* pA1 = A  + (long)(m0 + r1)*lda + ch1;
  const bf16* pB0 = Bm + (long)(n0 + r0)*ldb + ch0;
  const bf16* pB1 = Bm + (long)(n0 + r1)*ldb + ch1;
  auto stage = [&](int buf) {
    glds16(pA0, (void*)(&As[buf][i0*8]));
    glds16(pA1, (void*)(&As[buf][i1*8]));
    glds16(pB0, (void*)(&Bs[buf][i0*8]));
    glds16(pB1, (void*)(&Bs[buf][i1*8]));
    pA0 += 32; pA1 += 32; pB0 += 32; pB1 += 32;
  };

  stage(0);
  __builtin_amdgcn_s_waitcnt(0);
  __syncthreads();

  // fragment-read indices: row = base+l16, chunk = quad
  const int Rh = l16 >> 1;                  // (row>>1) & 7  (base is mult of 16)
  const int ppq = ((l16 & 1) << 2) | quad;  // cc
  const int jfr = ppq ^ Rh;                 // slot
  const int nsteps = K >> 5;
  for (int s = 0; s < nsteps; ++s) {
    const int cur = s & 1;
    if (s + 1 < nsteps) stage(cur ^ 1);

    bf16x8 af[4], bfr[4];
    #pragma unroll
    for (int mi = 0; mi < 4; ++mi)
      af[mi] = *(const bf16x8*)(&As[cur][(wy*32 + mi*8 + Rh)*64 + jfr*8]);
    #pragma unroll
    for (int ni = 0; ni < 4; ++ni)
      bfr[ni] = *(const bf16x8*)(&Bs[cur][(wx*32 + ni*8 + Rh)*64 + jfr*8]);
    #pragma unroll
    for (int mi = 0; mi < 4; ++mi)
      #pragma unroll
      for (int ni = 0; ni < 4; ++ni)
        acc[mi][ni] = mfma_bf16(af[mi], bfr[ni], acc[mi][ni]);

    __builtin_amdgcn_s_waitcnt(0);
    __syncthreads();
  }

  #pragma unroll
  for (int mi = 0; mi < 4; ++mi)
    #pragma unroll
    for (int ni = 0; ni < 4; ++ni) {
      int col = n0 + wx*64 + ni*16 + l16;
      #pragma unroll
      for (int r = 0; r < 4; ++r) {
        long row = m0 + wy*64 + mi*16 + quad*4 + r;
        float v = acc[mi][ni][r];
        if (BIAS) v += bias[col];
        if (RES)  v += res[row*ldc + col];
        if (RELU) v = v > 0.f ? v : 0.f;
        C[row*ldc + col] = (OutT)v;
      }
    }
}

// ---------------- 64x64-tile GEMM, BK=64, XOR-swizzled LDS --------------------
// 4 waves of 32Mx32N; conflict-free ds_read_b128; high block count for latency
// overlap (R8-verified). K % 64 == 0.
template<typename OutT, bool RELU, bool BIAS, bool RES>
__global__ __launch_bounds__(256) void gemm64(const bf16* __restrict__ A,
                                              const bf16* __restrict__ Bm,
                                              OutT* __restrict__ C,
                                              const float* __restrict__ bias,
                                              const float* __restrict__ res,
                                              int K, int lda, int ldb, int ldc)
{
  __shared__ bf16 As[2][64*64];
  __shared__ bf16 Bs[2][64*64];
  const int tid = threadIdx.x;
  int bx = blockIdx.x, by = blockIdx.y;
  swz_xy(bx, by);
  const int m0 = by * 64, n0 = bx * 64;
  const int w = tid >> 6, lane = tid & 63;
  const int quad = lane >> 4, l16 = lane & 15;
  const int wy = w >> 1, wx = w & 1;     // wave tile: 32M x 32N
  const int sw = l16 & 7;                // fragment-read swizzle

  f32x4 acc[2][2];
  #pragma unroll
  for (int i = 0; i < 2; i++)
    #pragma unroll
    for (int j = 0; j < 2; j++) acc[i][j] = (f32x4){0.f,0.f,0.f,0.f};

  const int c0 = tid, c1 = tid + 256;
  const int r0 = c0 >> 3, g0 = ((c0 & 7) ^ (r0 & 7)) * 8;
  const int r1 = c1 >> 3, g1 = ((c1 & 7) ^ (r1 & 7)) * 8;
  const bf16* pA0 = A  + (long)(m0 + r0)*lda + g0;
  const bf16* pA1 = A  + (long)(m0 + r1)*lda + g1;
  const bf16* pB0 = Bm + (long)(n0 + r0)*ldb + g0;
  const bf16* pB1 = Bm + (long)(n0 + r1)*ldb + g1;
  auto stage = [&](int buf) {
    glds16(pA0, (void*)(&As[buf][c0*8]));
    glds16(pA1, (void*)(&As[buf][c1*8]));
    glds16(pB0, (void*)(&Bs[buf][c0*8]));
    glds16(pB1, (void*)(&Bs[buf][c1*8]));
    pA0 += 64; pA1 += 64; pB0 += 64; pB1 += 64;
  };

  stage(0);
  __builtin_amdgcn_s_waitcnt(0);
  __syncthreads();

  const int nsteps = K >> 6;
  for (int s = 0; s < nsteps; ++s) {
    const int cur = s & 1;
    if (s + 1 < nsteps) stage(cur ^ 1);

    bf16x8 af[2][2], bfr[2][2];
    #pragma unroll
    for (int mi = 0; mi < 2; ++mi)
      #pragma unroll
      for (int kb = 0; kb < 2; ++kb)
        af[mi][kb] = *(const bf16x8*)(&As[cur][(wy*32 + mi*16 + l16)*64 + (((kb*4 + quad) ^ sw))*8]);
    #pragma unroll
    for (int ni = 0; ni < 2; ++ni)
      #pragma unroll
      for (int kb = 0; kb < 2; ++kb)
        bfr[ni][kb] = *(const bf16x8*)(&Bs[cur][(wx*32 + ni*16 + l16)*64 + (((kb*4 + quad) ^ sw))*8]);
    #pragma unroll
    for (int kb = 0; kb < 2; ++kb)
      #pragma unroll
      for (int mi = 0; mi < 2; ++mi)
        #pragma unroll
        for (int ni = 0; ni < 2; ++ni)
          acc[mi][ni] = mfma_bf16(af[mi][kb], bfr[ni][kb], acc[mi][ni]);

    __builtin_amdgcn_s_waitcnt(0);
    __syncthreads();
  }

  #pragma unroll
  for (int mi = 0; mi < 2; ++mi)
    #pragma unroll
    for (int ni = 0; ni < 2; ++ni) {
      int col = n0 + wx*32 + ni*16 + l16;
      #pragma unroll
      for (int r = 0; r < 4; ++r) {
        long row = m0 + wy*32 + mi*16 + quad*4 + r;
        float v = acc[mi][ni][r];
        if (BIAS) v += bias[col];
        if (RES)  v += res[row*ldc + col];
        if (RELU) v = v > 0.f ? v : 0.f;
        C[row*ldc + col] = (OutT)v;
      }
    }
}

// ---- QKV GEMM: 64x64-tile variant with split epilogue:
// cols<1536 -> Qkv[t][2304]; V block -> Vt[bh][d][s] directly.
__global__ __launch_bounds__(256) void gemm_qkv64(const bf16* __restrict__ A,
                                                  const bf16* __restrict__ Bm,
                                                  bf16* __restrict__ Qkv,
                                                  bf16* __restrict__ Vt)
{
  __shared__ bf16 As[2][64*64];
  __shared__ bf16 Bs[2][64*64];
  const int tid = threadIdx.x;
  int bx = blockIdx.x, by = blockIdx.y;
  swz_xy(bx, by);
  const int m0 = by * 64, n0 = bx * 64;
  const int w = tid >> 6, lane = tid & 63;
  const int quad = lane >> 4, l16 = lane & 15;
  const int wy = w >> 1, wx = w & 1;
  const int sw = l16 & 7;

  f32x4 acc[2][2];
  #pragma unroll
  for (int i = 0; i < 2; i++)
    #pragma unroll
    for (int j = 0; j < 2; j++) acc[i][j] = (f32x4){0.f,0.f,0.f,0.f};

  const int c0 = tid, c1 = tid + 256;
  const int r0 = c0 >> 3, g0 = ((c0 & 7) ^ (r0 & 7)) * 8;
  const int r1 = c1 >> 3, g1 = ((c1 & 7) ^ (r1 & 7)) * 8;
  const bf16* pA0 = A  + (long)(m0 + r0)*768 + g0;
  const bf16* pA1 = A  + (long)(m0 + r1)*768 + g1;
  const bf16* pB0 = Bm + (long)(n0 + r0)*768 + g0;
  const bf16* pB1 = Bm + (long)(n0 + r1)*768 + g1;
  auto stage = [&](int buf) {
    glds16(pA0, (void*)(&As[buf][c0*8]));
    glds16(pA1, (void*)(&As[buf][c1*8]));
    glds16(pB0, (void*)(&Bs[buf][c0*8]));
    glds16(pB1, (void*)(&Bs[buf][c1*8]));
    pA0 += 64; pA1 += 64; pB0 += 64; pB1 += 64;
  };

  stage(0);
  __builtin_amdgcn_s_waitcnt(0);
  __syncthreads();

  for (int s = 0; s < 12; ++s) {           // K=768
    const int cur = s & 1;
    if (s + 1 < 12) stage(cur ^ 1);

    bf16x8 af[2][2], bfr[2][2];
    #pragma unroll
    for (int mi = 0; mi < 2; ++mi)
      #pragma unroll
      for (int kb = 0; kb < 2; ++kb)
        af[mi][kb] = *(const bf16x8*)(&As[cur][(wy*32 + mi*16 + l16)*64 + (((kb*4 + quad) ^ sw))*8]);
    #pragma unroll
    for (int ni = 0; ni < 2; ++ni)
      #pragma unroll
      for (int kb = 0; kb < 2; ++kb)
        bfr[ni][kb] = *(const bf16x8*)(&Bs[cur][(wx*32 + ni*16 + l16)*64 + (((kb*4 + quad) ^ sw))*8]);
    #pragma unroll
    for (int kb = 0; kb < 2; ++kb)
      #pragma unroll
      for (int mi = 0; mi < 2; ++mi)
        #pragma unroll
        for (int ni = 0; ni < 2; ++ni)
          acc[mi][ni] = mfma_bf16(af[mi][kb], bfr[ni][kb], acc[mi][ni]);

    __builtin_amdgcn_s_waitcnt(0);
    __syncthreads();
  }

  const int bb = m0 >> 11;                  // batch (tile is 2048-aligned)
  #pragma unroll
  for (int mi = 0; mi < 2; ++mi)
    #pragma unroll
    for (int ni = 0; ni < 2; ++ni) {
      int col = n0 + wx*32 + ni*16 + l16;
      #pragma unroll
      for (int r = 0; r < 4; ++r) {
        long row = m0 + wy*32 + mi*16 + quad*4 + r;
        bf16 v = (bf16)acc[mi][ni][r];
        if (col < 1536) {
          Qkv[row*2304 + col] = v;
        } else {
          int vc = col - 1536;
          int hh = vc >> 6, d = vc & 63;
          long srow = row & (NS-1);
          Vt[((long)(bb*NHEAD + hh)*64 + d)*NS + srow] = v;
        }
      }
    }
}

// ---------------- flash attention v4 --------------------------------------------
// S^T = mfma(K, Q); P stays in registers as PV A-fragments (R6-verified mapping).
// lsum via ones-column MFMA (C-layout, no cross-lane reduce). KV loop unrolled
// x2 so `cur` is a literal (LDS addrs loop-invariant).
__global__ __launch_bounds__(256) void flash_attn(const bf16* __restrict__ Qkv,
                                                  const bf16* __restrict__ Vt,
                                                  bf16* __restrict__ Ctx)
{
  __shared__ bf16 Ks[2][64*64];
  __shared__ bf16 Vs[2][64*64];

  const int tid = threadIdx.x;
  const int w = tid >> 6, lane = tid & 63;
  const int quad = lane >> 4, l16 = lane & 15;
  const int bh = blockIdx.y;
  const int b = bh / NHEAD, h = bh % NHEAD;
  const int q0 = blockIdx.x * 64;
  const long tq = (long)(b*NS + q0 + w*16 + l16);

  bf16x8 qf[2];   // q pre-scaled by 0.125*log2e via Wqkv
  qf[0] = *(const bf16x8*)(Qkv + tq*2304 + h*64 + quad*8);
  qf[1] = *(const bf16x8*)(Qkv + tq*2304 + h*64 + 32 + quad*8);

  bf16x8 ones;
  #pragma unroll
  for (int j = 0; j < 8; ++j) ones[j] = (bf16)1.0f;

  f32x4 o[4];
  f32x4 o5 = (f32x4){0.f,0.f,0.f,0.f};
  #pragma unroll
  for (int i = 0; i < 4; i++) o[i] = (f32x4){0.f,0.f,0.f,0.f};

  const int c0 = tid, c1 = tid + 256;
  const int r0 = c0 >> 3, g0 = ((c0 & 7) ^ (r0 & 7)) * 8;
  const int r1 = c1 >> 3, g1 = ((c1 & 7) ^ (r1 & 7)) * 8;
  const bf16* kp0 = Qkv + (long)(b*NS + r0)*2304 + 768 + h*64 + g0;
  const bf16* kp1 = Qkv + (long)(b*NS + r1)*2304 + 768 + h*64 + g1;
  const bf16* vp0 = Vt + ((long)bh*64 + r0)*NS + g0;
  const bf16* vp1 = Vt + ((long)bh*64 + r1)*NS + g1;

  auto stage = [&](int buf) {
    glds16(kp0, (void*)(&Ks[buf][c0*8]));
    glds16(kp1, (void*)(&Ks[buf][c1*8]));
    glds16(vp0, (void*)(&Vs[buf][c0*8]));
    glds16(vp1, (void*)(&Vs[buf][c1*8]));
    kp0 += 64*2304; kp1 += 64*2304; vp0 += 64; vp1 += 64;
  };

  auto body = [&](int cur) {   // cur is a literal at every call site
    f32x4 s[4];
    #pragma unroll
    for (int nt = 0; nt < 4; ++nt) {
      s[nt] = (f32x4){0.f,0.f,0.f,0.f};
      #pragma unroll
      for (int kb = 0; kb < 2; ++kb) {
        bf16x8 kf = *(const bf16x8*)(&Ks[cur][(nt*16 + l16)*64 + (((kb*4 + quad) ^ (l16 & 7)))*8]);
        s[nt] = mfma_bf16(kf, qf[kb], s[nt]);   // A=K, B=Q -> S^T
      }
    }
    bf16x8 pf[2];
    #pragma unroll
    for (int nt = 0; nt < 4; ++nt)
      #pragma unroll
      for (int r = 0; r < 4; ++r)
        pf[nt >> 1][(nt & 1)*4 + r] = (bf16)fast_exp2(s[nt][r]);
    #pragma unroll
    for (int ntp = 0; ntp < 2; ++ntp) {
      #pragma unroll
      for (int dt = 0; dt < 4; ++dt) {
        int row = dt*16 + l16;                       // d
        int cA = ntp*4 + (quad >> 1);
        int base = row*64 + (quad & 1)*4;
        bf16x4 va = *(const bf16x4*)(&Vs[cur][base + ((cA       ^ (row & 7)) << 3)]);
        bf16x4 vb = *(const bf16x4*)(&Vs[cur][base + (((cA + 2) ^ (row & 7)) << 3)]);
        bf16x8 vf = {va[0],va[1],va[2],va[3], vb[0],vb[1],vb[2],vb[3]};
        o[dt] = mfma_bf16(pf[ntp], vf, o[dt]);
      }
      o5 = mfma_bf16(pf[ntp], ones, o5);           // lsum in C-layout
    }
  };

  stage(0);
  __builtin_amdgcn_s_waitcnt(0);
  __syncthreads();

  for (int t = 0; t < NS/64; t += 2) {
    stage(1);
    body(0);
    __builtin_amdgcn_s_waitcnt(0);
    __syncthreads();
    if (t + 2 < NS/64) stage(0);
    body(1);
    __builtin_amdgcn_s_waitcnt(0);
    __syncthreads();
  }

  #pragma unroll
  for (int r = 0; r < 4; ++r) {
    float inv = 1.f / o5[r];
    long trow = (long)(b*NS + q0 + w*16 + quad*4 + r);
    #pragma unroll
    for (int dt = 0; dt < 4; ++dt)
      Ctx[trow*NE + h*64 + dt*16 + l16] = (bf16)(o[dt][r] * inv);
  }
}

// ---------------- per-token: inter + build g/ones/zeros cols of Aext -----------
// 4 waves/block, one token per wave. Aext stride LDW; cols 1285..1343 zeroed.
__global__ __launch_bounds__(256) void build_g(const bf16* __restrict__ HAB,
                                               const float* __restrict__ P,
                                               const float* __restrict__ hB_b2,
                                               bf16* __restrict__ Aext)
{
  long t = blockIdx.x*4 + (threadIdx.x >> 6);
  int lane = threadIdx.x & 63;
  const bf16* xr = Aext + t*LDW;             // cols 0..767 = xn2
  float acc[4] = {0.f, 0.f, 0.f, 0.f};
  for (int i = lane; i < 768; i += 64) {
    float xv = (float)xr[i];
    #pragma unroll
    for (int r = 0; r < 4; ++r) acc[r] += xv * hB_b2[r*768 + i];
  }
  const bf16* hB = HAB + t*256 + 128;
  const float* Pr = P + t*512;
  #pragma unroll
  for (int k = 0; k < 2; ++k) {
    int h = lane + k*64;
    float hv = (float)hB[h];
    #pragma unroll
    for (int r = 0; r < 4; ++r) acc[r] += hv * Pr[r*128 + h];
  }
  #pragma unroll
  for (int r = 0; r < 4; ++r)
    #pragma unroll
    for (int d = 1; d < 64; d <<= 1) acc[r] += __shfl_xor(acc[r], d, 64);

  bf16* grow = Aext + t*LDW + 768;
  const bf16* hA = HAB + t*256;
  #pragma unroll
  for (int j = 0; j < 8; ++j) {
    int idx = lane*8 + j;                    // 0..511
    int h = idx >> 2, r = idx & 3;
    grow[idx] = (bf16)((float)hA[h] * acc[r]);
  }
  if (lane < 4)       Aext[t*LDW + 1280 + lane] = (bf16)acc[lane];
  else if (lane == 4) Aext[t*LDW + 1284] = (bf16)1.0f;
  else                Aext[t*LDW + 1280 + lane] = (bf16)0.f;   // 1285..1343
}

// ---------------- host launcher ----------------
extern "C" void kernel_launch(void* const* d_in, const int* in_sizes, int n_in,
                              void* d_out, int out_size, void* d_ws, size_t ws_size,
                              hipStream_t stream)
{
  const float* src      = (const float*)d_in[0];
  const float* task     = (const float*)d_in[1];
  const float* norm1_w  = (const float*)d_in[2];
  const float* norm2_w  = (const float*)d_in[3];
  const float* in_proj  = (const float*)d_in[4];
  const float* out_proj = (const float*)d_in[5];
  const float* ffn1_w   = (const float*)d_in[6];
  const float* ffn1_b   = (const float*)d_in[7];
  const float* ffn2_w   = (const float*)d_in[8];
  const float* ffn2_b   = (const float*)d_in[9];
  const float* hA_w1    = (const float*)d_in[10];
  const float* hA_b1    = (const float*)d_in[11];
  const float* hA_w2    = (const float*)d_in[12];
  const float* hA_b2    = (const float*)d_in[13];
  const float* hB_w1    = (const float*)d_in[14];
  const float* hB_b1    = (const float*)d_in[15];
  const float* hB_w2    = (const float*)d_in[16];
  const float* hB_b2    = (const float*)d_in[17];
  float* out = (float*)d_out;

  char* ws = (char*)d_ws;
  size_t off = 0;
  auto alloc = [&](size_t bytes) { size_t o = off; off += (bytes + 255) & ~(size_t)255; return o; };
  bf16*  Wqkv   = (bf16*)(ws + alloc(2304*768*2));
  bf16*  Wo     = (bf16*)(ws + alloc(768*768*2));
  bf16*  W2     = (bf16*)(ws + alloc(768*3072*2));
  bf16*  W1ab   = (bf16*)(ws + alloc(256*128*2));
  float* b1ab   = (float*)(ws + alloc(256*4));
  bf16*  WBp    = (bf16*)(ws + alloc(512*768*2));
  bf16*  Wc     = (bf16*)(ws + alloc((size_t)3072*LDW*2));
  bf16*  taskbf = (bf16*)(ws + alloc((size_t)NTOK*128*2));
  bf16*  XC     = (bf16*)(ws + alloc((size_t)NTOK*768*2));    // Xn1, then Ctx
  char*  QKVH   = ws + alloc(25165824);                        // Qkv(18874368)+Vt(6291456) / Hbuf
  bf16*  Qkv    = (bf16*)QKVH;
  bf16*  Vt     = (bf16*)(QKVH + 18874368);
  bf16*  Hbuf   = (bf16*)QKVH;
  float* Src2   = (float*)(ws + alloc((size_t)NTOK*768*4));
  bf16*  Aext   = (bf16*)(ws + alloc((size_t)NTOK*LDW*2));
  bf16*  HAB    = (bf16*)(ws + alloc((size_t)NTOK*256*2));
  float* P      = (float*)(ws + alloc((size_t)NTOK*512*4));

  // K0: weight prep / casts
  prep_kernel<<<dim3(1280), 256, 0, stream>>>(in_proj, out_proj, ffn1_w, ffn1_b, ffn2_w,
      hA_w1, hA_b1, hA_w2, hA_b2, hB_w1, hB_b1, hB_w2, task,
      Wqkv, Wo, W2, W1ab, b1ab, WBp, Wc, taskbf);
  // K1: x1 = rmsnorm(src, norm1_w) -> bf16
  rmsnorm_k<<<dim3(NTOK), 256, 0, stream>>>(src, norm1_w, XC, 768);
  // K2: qkv = x1 @ in_proj^T ; V block written directly to Vt
  gemm_qkv64<<<dim3(36,64), 256, 0, stream>>>(XC, Wqkv, Qkv, Vt);
  // K4: flash attention -> Ctx (reuses XC)
  flash_attn<<<dim3(32,24), 256, 0, stream>>>(Qkv, Vt, XC);
  // K5: src2 = src + ctx @ out_proj^T
  gemm64<float,false,false,true><<<dim3(12,64), 256, 0, stream>>>(XC, Wo, Src2, nullptr, src, 768, 768, 768, 768);
  // K6: xn2 = rmsnorm(src2, norm2_w) -> Aext cols 0..767 (stride LDW)
  rmsnorm_k<<<dim3(NTOK), 256, 0, stream>>>(Src2, norm2_w, Aext, LDW);
  // K7: HAB = relu(task @ W1ab^T + b1ab)
  gemm64<bf16,true,true,false><<<dim3(4,64), 256, 0, stream>>>(taskbf, W1ab, HAB, b1ab, nullptr, 128, 128, 128, 256);
  // K8: P = xn2 @ WBp^T
  gemm64<float,false,false,false><<<dim3(8,64), 256, 0, stream>>>(Aext, WBp, P, nullptr, nullptr, 768, LDW, 768, 512);
  // K9: inter + g -> Aext cols 768..1343
  build_g<<<dim3(NTOK/4), 256, 0, stream>>>(HAB, P, hB_b2, Aext);
  // K10: H = relu(Aext @ Wc^T)  (128-tile, conflict-free swizzled LDS, K=1312)
  gemm_bt_sw<bf16,true,false,false><<<dim3(24,32), 256, 0, stream>>>(Aext, Wc, Hbuf, nullptr, nullptr, 1312, LDW, LDW, 3072);
  // K11: out = src2 + H @ ffn2_w^T + ffn2_b
  gemm64<float,false,true,true><<<dim3(12,64), 256, 0, stream>>>(Hbuf, W2, out, ffn2_b, Src2, 3072, 3072, 3072, 768);
}

// Round 11
// 324.875 us; speedup vs baseline: 1.0357x; 1.0089x over previous
//
#include <hip/hip_runtime.h>
#include <math.h>

// ---- problem constants ----
#define NB 2
#define NS 2048
#define NE 768
#define NF 3072
#define NHEAD 12
#define NTOK 4096   // B*S
#define LDW 1344    // padded inner dim for Aext/Wc (21*64)

typedef __bf16 bf16;
typedef __bf16 bf16x4 __attribute__((ext_vector_type(4)));
typedef __bf16 bf16x8 __attribute__((ext_vector_type(8)));
typedef float  f32x4  __attribute__((ext_vector_type(4)));

__device__ __forceinline__ f32x4 mfma_bf16(bf16x8 a, bf16x8 b, f32x4 c) {
  return __builtin_amdgcn_mfma_f32_16x16x32_bf16(a, b, c, 0, 0, 0);
}

__device__ __forceinline__ float fast_exp2(float x) {
#if __has_builtin(__builtin_amdgcn_exp2f)
  return __builtin_amdgcn_exp2f(x);
#else
  return exp2f(x);
#endif
}

// async global->LDS, 16B per lane. LDS dest must be wave-uniform base + lane*16.
__device__ __forceinline__ void glds16(const void* g, void* l) {
  __builtin_amdgcn_global_load_lds((const __attribute__((address_space(1))) void*)g,
                                   (__attribute__((address_space(3))) void*)l,
                                   16, 0, 0);
}

// XCD-band swizzle (gridDim.y % 8 == 0 at all call sites).
__device__ __forceinline__ void swz_xy(int& bx, int& by) {
  int gx = gridDim.x;
  int i = by*gx + bx;
  int xcd = i & 7, s = i >> 3;
  int bands = gridDim.y >> 3;
  by = xcd*bands + s / gx;
  bx = s % gx;
}

// ---------------- weight prep: fp32 -> bf16 (+ reshapes/concat) ----------------
__global__ void prep_kernel(const float* __restrict__ in_proj, const float* __restrict__ out_proj,
                            const float* __restrict__ ffn1_w, const float* __restrict__ ffn1_b,
                            const float* __restrict__ ffn2_w,
                            const float* __restrict__ hA_w1, const float* __restrict__ hA_b1,
                            const float* __restrict__ hA_w2, const float* __restrict__ hA_b2,
                            const float* __restrict__ hB_w1, const float* __restrict__ hB_b1,
                            const float* __restrict__ hB_w2,
                            const float* __restrict__ task,
                            bf16* __restrict__ Wqkv, bf16* __restrict__ Wo, bf16* __restrict__ W2,
                            bf16* __restrict__ W1ab, float* __restrict__ b1ab,
                            bf16* __restrict__ WBp, bf16* __restrict__ Wc,
                            bf16* __restrict__ task_bf)
{
  __shared__ float tb[64*130];
  int stride = gridDim.x * blockDim.x;
  int t0 = blockIdx.x * blockDim.x + threadIdx.x;
  // q rows (first 768) pre-scaled by (1/sqrt(HD)) * log2(e) so flash can use exp2
  const float QS = 0.125f * 1.44269504088896f;
  // vectorized fp32->bf16 casts (float4 in, bf16x4 out)
  for (int i = t0; i < (2304*768)/4; i += stride) {
    float4 v = ((const float4*)in_proj)[i];
    float sc = (i < (768*768)/4) ? QS : 1.0f;
    *(bf16x4*)(Wqkv + i*4) = (bf16x4){(bf16)(v.x*sc), (bf16)(v.y*sc), (bf16)(v.z*sc), (bf16)(v.w*sc)};
  }
  for (int i = t0; i < (768*768)/4; i += stride) {
    float4 v = ((const float4*)out_proj)[i];
    *(bf16x4*)(Wo + i*4) = (bf16x4){(bf16)v.x, (bf16)v.y, (bf16)v.z, (bf16)v.w};
  }
  for (int i = t0; i < (768*3072)/4; i += stride) {
    float4 v = ((const float4*)ffn2_w)[i];
    *(bf16x4*)(W2 + i*4) = (bf16x4){(bf16)v.x, (bf16)v.y, (bf16)v.z, (bf16)v.w};
  }
  for (int i = t0; i < (NTOK*128)/4; i += stride) {
    float4 v = ((const float4*)task)[i];
    *(bf16x4*)(task_bf + i*4) = (bf16x4){(bf16)v.x, (bf16)v.y, (bf16)v.z, (bf16)v.w};
  }
  for (int i = t0; i < 256*128;  i += stride)
    W1ab[i] = (bf16)(i < 128*128 ? hA_w1[i] : hB_w1[i - 128*128]);
  for (int i = t0; i < 256; i += stride) b1ab[i] = (i < 128) ? hA_b1[i] : hB_b1[i-128];

  // WBp[n=(r*128+h)][e] = hB_w2[r*768+e][h] via 64x128 LDS transpose
  for (int j0 = blockIdx.x*64; j0 < 3072; j0 += gridDim.x*64) {
    __syncthreads();
    for (int i = threadIdx.x; i < 64*128; i += 256) {
      int jr = i >> 7, hh = i & 127;
      tb[jr*130 + hh] = hB_w2[(long)(j0 + jr)*128 + hh];
    }
    __syncthreads();
    int r = j0 / 768, e0 = j0 % 768;
    for (int i = threadIdx.x; i < 128*64; i += 256) {
      int hh = i >> 6, jr = i & 63;
      WBp[(long)(r*128 + hh)*768 + e0 + jr] = (bf16)tb[jr*130 + hh];
    }
  }

  // Wc[f][0:768]=ffn1_w ; [768+h*4+r]=hA_w2[(f*4+r)][h] ; [1280+r]=hA_b2[f*4+r] ;
  // [1284]=ffn1_b[f] ; [1285:1344]=0.  (stride LDW=1344)
  for (int f = blockIdx.x; f < 3072; f += gridDim.x) {
    const float* hrow = hA_w2 + (long)f*512;
    bf16* wrow = Wc + (long)f*LDW;
    for (int c = threadIdx.x; c < 768; c += 256) wrow[c] = (bf16)ffn1_w[(long)f*768 + c];
    for (int i = threadIdx.x; i < 512; i += 256) {
      int r = i >> 7, h = i & 127;
      wrow[768 + h*4 + r] = (bf16)hrow[i];
    }
    if (threadIdx.x < 4)        wrow[1280 + threadIdx.x] = (bf16)hA_b2[f*4 + threadIdx.x];
    else if (threadIdx.x == 4)  wrow[1284] = (bf16)ffn1_b[f];
    else if (threadIdx.x < 64)  wrow[1280 + threadIdx.x] = (bf16)0.f;
  }
}

// ---------------- RMSNorm (fp32 in -> bf16 out, arbitrary out row stride) ------
__global__ __launch_bounds__(256) void rmsnorm_k(const float* __restrict__ x,
                                                 const float* __restrict__ w,
                                                 bf16* __restrict__ out, int ld_out)
{
  __shared__ float red[4];
  long t = blockIdx.x;
  const float* xr = x + t*NE;
  float ss = 0.f;
  #pragma unroll
  for (int i = 0; i < 3; i++) { float v = xr[threadIdx.x + i*256]; ss += v*v; }
  #pragma unroll
  for (int d = 1; d < 64; d <<= 1) ss += __shfl_xor(ss, d, 64);
  if ((threadIdx.x & 63) == 0) red[threadIdx.x >> 6] = ss;
  __syncthreads();
  float tot = red[0] + red[1] + red[2] + red[3];
  float scale = rsqrtf(tot * (1.f/768.f) + 1.1920928955078125e-07f);
  #pragma unroll
  for (int i = 0; i < 3; i++) {
    int idx = threadIdx.x + i*256;
    out[t*ld_out + idx] = (bf16)(xr[idx] * scale * w[idx]);
  }
}

// ------- 128x128 BK=32 GEMM, conflict-free superrow-swizzled LDS ---------------
// (R10-verified: FETCH 37.7MB, 0 conflicts.) Element (row r, chunk c) at
// R=r>>1, slot j=((r&1)*4+c)^(R&7), offset R*128B + j*16B.
template<typename OutT, bool RELU, bool BIAS, bool RES>
__global__ __launch_bounds__(256) void gemm_bt_sw(const bf16* __restrict__ A,
                                                  const bf16* __restrict__ Bm,
                                                  OutT* __restrict__ C,
                                                  const float* __restrict__ bias,
                                                  const float* __restrict__ res,
                                                  int K, int lda, int ldb, int ldc)
{
  __shared__ bf16 As[2][128*32];
  __shared__ bf16 Bs[2][128*32];
  const int tid = threadIdx.x;
  int bx = blockIdx.x, by = blockIdx.y;
  swz_xy(bx, by);
  const int m0 = by * 128;
  const int n0 = bx * 128;
  const int w = tid >> 6, lane = tid & 63;
  const int quad = lane >> 4, l16 = lane & 15;
  const int wy = w >> 1, wx = w & 1;

  f32x4 acc[4][4];
  #pragma unroll
  for (int i = 0; i < 4; i++)
    #pragma unroll
    for (int j = 0; j < 4; j++) acc[i][j] = (f32x4){0.f,0.f,0.f,0.f};

  const int i0 = tid, i1 = tid + 256;
  const int R0 = i0 >> 3, cc0 = (i0 & 7) ^ (R0 & 7), r0 = 2*R0 + (cc0 >> 2), ch0 = (cc0 & 3) * 8;
  const int R1 = i1 >> 3, cc1 = (i1 & 7) ^ (R1 & 7), r1 = 2*R1 + (cc1 >> 2), ch1 = (cc1 & 3) * 8;
  const bf16* pA0 = A  + (long)(m0 + r0)*lda + ch0;
  const bf16* pA1 = A  + (long)(m0 + r1)*lda + ch1;
  const bf16* pB0 = Bm + (long)(n0 + r0)*ldb + ch0;
  const bf16* pB1 = Bm + (long)(n0 + r1)*ldb + ch1;
  auto stage = [&](int buf) {
    glds16(pA0, (void*)(&As[buf][i0*8]));
    glds16(pA1, (void*)(&As[buf][i1*8]));
    glds16(pB0, (void*)(&Bs[buf][i0*8]));
    glds16(pB1, (void*)(&Bs[buf][i1*8]));
    pA0 += 32; pA1 += 32; pB0 += 32; pB1 += 32;
  };

  stage(0);
  __builtin_amdgcn_s_waitcnt(0);
  __syncthreads();

  const int Rh = l16 >> 1;
  const int ppq = ((l16 & 1) << 2) | quad;
  const int jfr = ppq ^ Rh;
  const int nsteps = K >> 5;
  for (int s = 0; s < nsteps; ++s) {
    const int cur = s & 1;
    if (s + 1 < nsteps) stage(cur ^ 1);

    bf16x8 af[4], bfr[4];
    #pragma unroll
    for (int mi = 0; mi < 4; ++mi)
      af[mi] = *(const bf16x8*)(&As[cur][(wy*32 + mi*8 + Rh)*64 + jfr*8]);
    #pragma unroll
    for (int ni = 0; ni < 4; ++ni)
      bfr[ni] = *(const bf16x8*)(&Bs[cur][(wx*32 + ni*8 + Rh)*64 + jfr*8]);
    #pragma unroll
    for (int mi = 0; mi < 4; ++mi)
      #pragma unroll
      for (int ni = 0; ni < 4; ++ni)
        acc[mi][ni] = mfma_bf16(af[mi], bfr[ni], acc[mi][ni]);

    __builtin_amdgcn_s_waitcnt(0);
    __syncthreads();
  }

  #pragma unroll
  for (int mi = 0; mi < 4; ++mi)
    #pragma unroll
    for (int ni = 0; ni < 4; ++ni) {
      int col = n0 + wx*64 + ni*16 + l16;
      #pragma unroll
      for (int r = 0; r < 4; ++r) {
        long row = m0 + wy*64 + mi*16 + quad*4 + r;
        float v = acc[mi][ni][r];
        if (BIAS) v += bias[col];
        if (RES)  v += res[row*ldc + col];
        if (RELU) v = v > 0.f ? v : 0.f;
        C[row*ldc + col] = (OutT)v;
      }
    }
}

// ---------------- 64x64-tile GEMM, BK=64, XOR-swizzled LDS --------------------
template<typename OutT, bool RELU, bool BIAS, bool RES>
__global__ __launch_bounds__(256) void gemm64(const bf16* __restrict__ A,
                                              const bf16* __restrict__ Bm,
                                              OutT* __restrict__ C,
                                              const float* __restrict__ bias,
                                              const float* __restrict__ res,
                                              int K, int lda, int ldb, int ldc)
{
  __shared__ bf16 As[2][64*64];
  __shared__ bf16 Bs[2][64*64];
  const int tid = threadIdx.x;
  int bx = blockIdx.x, by = blockIdx.y;
  swz_xy(bx, by);
  const int m0 = by * 64, n0 = bx * 64;
  const int w = tid >> 6, lane = tid & 63;
  const int quad = lane >> 4, l16 = lane & 15;
  const int wy = w >> 1, wx = w & 1;
  const int sw = l16 & 7;

  f32x4 acc[2][2];
  #pragma unroll
  for (int i = 0; i < 2; i++)
    #pragma unroll
    for (int j = 0; j < 2; j++) acc[i][j] = (f32x4){0.f,0.f,0.f,0.f};

  const int c0 = tid, c1 = tid + 256;
  const int r0 = c0 >> 3, g0 = ((c0 & 7) ^ (r0 & 7)) * 8;
  const int r1 = c1 >> 3, g1 = ((c1 & 7) ^ (r1 & 7)) * 8;
  const bf16* pA0 = A  + (long)(m0 + r0)*lda + g0;
  const bf16* pA1 = A  + (long)(m0 + r1)*lda + g1;
  const bf16* pB0 = Bm + (long)(n0 + r0)*ldb + g0;
  const bf16* pB1 = Bm + (long)(n0 + r1)*ldb + g1;
  auto stage = [&](int buf) {
    glds16(pA0, (void*)(&As[buf][c0*8]));
    glds16(pA1, (void*)(&As[buf][c1*8]));
    glds16(pB0, (void*)(&Bs[buf][c0*8]));
    glds16(pB1, (void*)(&Bs[buf][c1*8]));
    pA0 += 64; pA1 += 64; pB0 += 64; pB1 += 64;
  };

  stage(0);
  __builtin_amdgcn_s_waitcnt(0);
  __syncthreads();

  const int nsteps = K >> 6;
  for (int s = 0; s < nsteps; ++s) {
    const int cur = s & 1;
    if (s + 1 < nsteps) stage(cur ^ 1);

    bf16x8 af[2][2], bfr[2][2];
    #pragma unroll
    for (int mi = 0; mi < 2; ++mi)
      #pragma unroll
      for (int kb = 0; kb < 2; ++kb)
        af[mi][kb] = *(const bf16x8*)(&As[cur][(wy*32 + mi*16 + l16)*64 + (((kb*4 + quad) ^ sw))*8]);
    #pragma unroll
    for (int ni = 0; ni < 2; ++ni)
      #pragma unroll
      for (int kb = 0; kb < 2; ++kb)
        bfr[ni][kb] = *(const bf16x8*)(&Bs[cur][(wx*32 + ni*16 + l16)*64 + (((kb*4 + quad) ^ sw))*8]);
    #pragma unroll
    for (int kb = 0; kb < 2; ++kb)
      #pragma unroll
      for (int mi = 0; mi < 2; ++mi)
        #pragma unroll
        for (int ni = 0; ni < 2; ++ni)
          acc[mi][ni] = mfma_bf16(af[mi][kb], bfr[ni][kb], acc[mi][ni]);

    __builtin_amdgcn_s_waitcnt(0);
    __syncthreads();
  }

  #pragma unroll
  for (int mi = 0; mi < 2; ++mi)
    #pragma unroll
    for (int ni = 0; ni < 2; ++ni) {
      int col = n0 + wx*32 + ni*16 + l16;
      #pragma unroll
      for (int r = 0; r < 4; ++r) {
        long row = m0 + wy*32 + mi*16 + quad*4 + r;
        float v = acc[mi][ni][r];
        if (BIAS) v += bias[col];
        if (RES)  v += res[row*ldc + col];
        if (RELU) v = v > 0.f ? v : 0.f;
        C[row*ldc + col] = (OutT)v;
      }
    }
}

// ---- QKV GEMM: 64x64-tile variant with split epilogue:
// cols<1536 -> Qkv[t][2304]; V block -> Vt[bh][d][s] directly.
__global__ __launch_bounds__(256) void gemm_qkv64(const bf16* __restrict__ A,
                                                  const bf16* __restrict__ Bm,
                                                  bf16* __restrict__ Qkv,
                                                  bf16* __restrict__ Vt)
{
  __shared__ bf16 As[2][64*64];
  __shared__ bf16 Bs[2][64*64];
  const int tid = threadIdx.x;
  int bx = blockIdx.x, by = blockIdx.y;
  swz_xy(bx, by);
  const int m0 = by * 64, n0 = bx * 64;
  const int w = tid >> 6, lane = tid & 63;
  const int quad = lane >> 4, l16 = lane & 15;
  const int wy = w >> 1, wx = w & 1;
  const int sw = l16 & 7;

  f32x4 acc[2][2];
  #pragma unroll
  for (int i = 0; i < 2; i++)
    #pragma unroll
    for (int j = 0; j < 2; j++) acc[i][j] = (f32x4){0.f,0.f,0.f,0.f};

  const int c0 = tid, c1 = tid + 256;
  const int r0 = c0 >> 3, g0 = ((c0 & 7) ^ (r0 & 7)) * 8;
  const int r1 = c1 >> 3, g1 = ((c1 & 7) ^ (r1 & 7)) * 8;
  const bf16* pA0 = A  + (long)(m0 + r0)*768 + g0;
  const bf16* pA1 = A  + (long)(m0 + r1)*768 + g1;
  const bf16* pB0 = Bm + (long)(n0 + r0)*768 + g0;
  const bf16* pB1 = Bm + (long)(n0 + r1)*768 + g1;
  auto stage = [&](int buf) {
    glds16(pA0, (void*)(&As[buf][c0*8]));
    glds16(pA1, (void*)(&As[buf][c1*8]));
    glds16(pB0, (void*)(&Bs[buf][c0*8]));
    glds16(pB1, (void*)(&Bs[buf][c1*8]));
    pA0 += 64; pA1 += 64; pB0 += 64; pB1 += 64;
  };

  stage(0);
  __builtin_amdgcn_s_waitcnt(0);
  __syncthreads();

  for (int s = 0; s < 12; ++s) {           // K=768
    const int cur = s & 1;
    if (s + 1 < 12) stage(cur ^ 1);

    bf16x8 af[2][2], bfr[2][2];
    #pragma unroll
    for (int mi = 0; mi < 2; ++mi)
      #pragma unroll
      for (int kb = 0; kb < 2; ++kb)
        af[mi][kb] = *(const bf16x8*)(&As[cur][(wy*32 + mi*16 + l16)*64 + (((kb*4 + quad) ^ sw))*8]);
    #pragma unroll
    for (int ni = 0; ni < 2; ++ni)
      #pragma unroll
      for (int kb = 0; kb < 2; ++kb)
        bfr[ni][kb] = *(const bf16x8*)(&Bs[cur][(wx*32 + ni*16 + l16)*64 + (((kb*4 + quad) ^ sw))*8]);
    #pragma unroll
    for (int kb = 0; kb < 2; ++kb)
      #pragma unroll
      for (int mi = 0; mi < 2; ++mi)
        #pragma unroll
        for (int ni = 0; ni < 2; ++ni)
          acc[mi][ni] = mfma_bf16(af[mi][kb], bfr[ni][kb], acc[mi][ni]);

    __builtin_amdgcn_s_waitcnt(0);
    __syncthreads();
  }

  const int bb = m0 >> 11;                  // batch (tile is 2048-aligned)
  #pragma unroll
  for (int mi = 0; mi < 2; ++mi)
    #pragma unroll
    for (int ni = 0; ni < 2; ++ni) {
      int col = n0 + wx*32 + ni*16 + l16;
      #pragma unroll
      for (int r = 0; r < 4; ++r) {
        long row = m0 + wy*32 + mi*16 + quad*4 + r;
        bf16 v = (bf16)acc[mi][ni][r];
        if (col < 1536) {
          Qkv[row*2304 + col] = v;
        } else {
          int vc = col - 1536;
          int hh = vc >> 6, d = vc & 63;
          long srow = row & (NS-1);
          Vt[((long)(bb*NHEAD + hh)*64 + d)*NS + srow] = v;
        }
      }
    }
}

// ---------------- flash attention v5: 2 waves/block, 32 q-rows/wave -------------
// Halves per-tile block-level LDS read bytes (K-frags loaded once, shared by
// both q-groups in registers; V-frags reused across q-groups) -> the LDS pipe
// stops being the per-tile floor. S^T = mfma(K,Q); register-resident P; lsum
// via ones-MFMA; q pre-scaled 0.125*log2e; XOR-swizzled K/V, dbuf staging.
__global__ __launch_bounds__(128) void flash_attn(const bf16* __restrict__ Qkv,
                                                  const bf16* __restrict__ Vt,
                                                  bf16* __restrict__ Ctx)
{
  __shared__ bf16 Ks[2][64*64];
  __shared__ bf16 Vs[2][64*64];

  const int tid = threadIdx.x;
  const int w = tid >> 6, lane = tid & 63;
  const int quad = lane >> 4, l16 = lane & 15;
  const int bh = blockIdx.y;
  const int b = bh / NHEAD, h = bh % NHEAD;
  const int q0 = blockIdx.x * 64;

  bf16x8 qf[2][2];   // [q-group][kb]
  #pragma unroll
  for (int mi = 0; mi < 2; ++mi) {
    const long tq = (long)(b*NS + q0 + w*32 + mi*16 + l16);
    qf[mi][0] = *(const bf16x8*)(Qkv + tq*2304 + h*64 + quad*8);
    qf[mi][1] = *(const bf16x8*)(Qkv + tq*2304 + h*64 + 32 + quad*8);
  }

  bf16x8 ones;
  #pragma unroll
  for (int j = 0; j < 8; ++j) ones[j] = (bf16)1.0f;

  f32x4 o[2][4];
  f32x4 o5[2];
  #pragma unroll
  for (int mi = 0; mi < 2; ++mi) {
    o5[mi] = (f32x4){0.f,0.f,0.f,0.f};
    #pragma unroll
    for (int i = 0; i < 4; i++) o[mi][i] = (f32x4){0.f,0.f,0.f,0.f};
  }

  // staging: 128 threads x 4 chunks each for K and V (512 chunks = 64x64 tile)
  const bf16* kp[4];
  const bf16* vp[4];
  int cc[4];
  #pragma unroll
  for (int i = 0; i < 4; ++i) {
    int c = tid + i*128;
    cc[i] = c;
    int r = c >> 3, g = ((c & 7) ^ (r & 7)) * 8;
    kp[i] = Qkv + (long)(b*NS + r)*2304 + 768 + h*64 + g;
    vp[i] = Vt + ((long)bh*64 + r)*NS + g;
  }
  auto stage = [&](int buf) {
    #pragma unroll
    for (int i = 0; i < 4; ++i) {
      glds16(kp[i], (void*)(&Ks[buf][cc[i]*8]));
      glds16(vp[i], (void*)(&Vs[buf][cc[i]*8]));
      kp[i] += 64*2304; vp[i] += 64;
    }
  };

  auto body = [&](int cur) {   // cur is a literal at every call site
    // K-fragments loaded once, reused by both q-groups
    bf16x8 kfr[4][2];
    #pragma unroll
    for (int nt = 0; nt < 4; ++nt)
      #pragma unroll
      for (int kb = 0; kb < 2; ++kb)
        kfr[nt][kb] = *(const bf16x8*)(&Ks[cur][(nt*16 + l16)*64 + (((kb*4 + quad) ^ (l16 & 7)))*8]);

    bf16x8 pf[2][2];   // [q-group][ntp]
    #pragma unroll
    for (int mi = 0; mi < 2; ++mi) {
      f32x4 s[4];
      #pragma unroll
      for (int nt = 0; nt < 4; ++nt) {
        s[nt] = (f32x4){0.f,0.f,0.f,0.f};
        #pragma unroll
        for (int kb = 0; kb < 2; ++kb)
          s[nt] = mfma_bf16(kfr[nt][kb], qf[mi][kb], s[nt]);   // A=K, B=Q -> S^T
      }
      #pragma unroll
      for (int nt = 0; nt < 4; ++nt)
        #pragma unroll
        for (int r = 0; r < 4; ++r)
          pf[mi][nt >> 1][(nt & 1)*4 + r] = (bf16)fast_exp2(s[nt][r]);
    }
    // PV: V-fragments loaded once per ntp, reused by both q-groups
    #pragma unroll
    for (int ntp = 0; ntp < 2; ++ntp) {
      bf16x8 vf[4];
      #pragma unroll
      for (int dt = 0; dt < 4; ++dt) {
        int row = dt*16 + l16;                       // d
        int cA = ntp*4 + (quad >> 1);
        int base = row*64 + (quad & 1)*4;
        bf16x4 va = *(const bf16x4*)(&Vs[cur][base + ((cA       ^ (row & 7)) << 3)]);
        bf16x4 vb = *(const bf16x4*)(&Vs[cur][base + (((cA + 2) ^ (row & 7)) << 3)]);
        vf[dt] = (bf16x8){va[0],va[1],va[2],va[3], vb[0],vb[1],vb[2],vb[3]};
      }
      #pragma unroll
      for (int mi = 0; mi < 2; ++mi) {
        #pragma unroll
        for (int dt = 0; dt < 4; ++dt)
          o[mi][dt] = mfma_bf16(pf[mi][ntp], vf[dt], o[mi][dt]);
        o5[mi] = mfma_bf16(pf[mi][ntp], ones, o5[mi]);   // lsum in C-layout
      }
    }
  };

  stage(0);
  __builtin_amdgcn_s_waitcnt(0);
  __syncthreads();

  for (int t = 0; t < NS/64; t += 2) {
    stage(1);
    body(0);
    __builtin_amdgcn_s_waitcnt(0);
    __syncthreads();
    if (t + 2 < NS/64) stage(0);
    body(1);
    __builtin_amdgcn_s_waitcnt(0);
    __syncthreads();
  }

  #pragma unroll
  for (int mi = 0; mi < 2; ++mi)
    #pragma unroll
    for (int r = 0; r < 4; ++r) {
      float inv = 1.f / o5[mi][r];
      long trow = (long)(b*NS + q0 + w*32 + mi*16 + quad*4 + r);
      #pragma unroll
      for (int dt = 0; dt < 4; ++dt)
        Ctx[trow*NE + h*64 + dt*16 + l16] = (bf16)(o[mi][dt][r] * inv);
    }
}

// ---------------- per-token: inter + build g/ones/zeros cols of Aext -----------
// 4 waves/block, one token per wave. Aext stride LDW; cols 1285..1343 zeroed.
__global__ __launch_bounds__(256) void build_g(const bf16* __restrict__ HAB,
                                               const float* __restrict__ P,
                                               const float* __restrict__ hB_b2,
                                               bf16* __restrict__ Aext)
{
  long t = blockIdx.x*4 + (threadIdx.x >> 6);
  int lane = threadIdx.x & 63;
  const bf16* xr = Aext + t*LDW;             // cols 0..767 = xn2
  float acc[4] = {0.f, 0.f, 0.f, 0.f};
  for (int i = lane; i < 768; i += 64) {
    float xv = (float)xr[i];
    #pragma unroll
    for (int r = 0; r < 4; ++r) acc[r] += xv * hB_b2[r*768 + i];
  }
  const bf16* hB = HAB + t*256 + 128;
  const float* Pr = P + t*512;
  #pragma unroll
  for (int k = 0; k < 2; ++k) {
    int h = lane + k*64;
    float hv = (float)hB[h];
    #pragma unroll
    for (int r = 0; r < 4; ++r) acc[r] += hv * Pr[r*128 + h];
  }
  #pragma unroll
  for (int r = 0; r < 4; ++r)
    #pragma unroll
    for (int d = 1; d < 64; d <<= 1) acc[r] += __shfl_xor(acc[r], d, 64);

  bf16* grow = Aext + t*LDW + 768;
  const bf16* hA = HAB + t*256;
  #pragma unroll
  for (int j = 0; j < 8; ++j) {
    int idx = lane*8 + j;                    // 0..511
    int h = idx >> 2, r = idx & 3;
    grow[idx] = (bf16)((float)hA[h] * acc[r]);
  }
  if (lane < 4)       Aext[t*LDW + 1280 + lane] = (bf16)acc[lane];
  else if (lane == 4) Aext[t*LDW + 1284] = (bf16)1.0f;
  else                Aext[t*LDW + 1280 + lane] = (bf16)0.f;   // 1285..1343
}

// ---------------- host launcher ----------------
extern "C" void kernel_launch(void* const* d_in, const int* in_sizes, int n_in,
                              void* d_out, int out_size, void* d_ws, size_t ws_size,
                              hipStream_t stream)
{
  const float* src      = (const float*)d_in[0];
  const float* task     = (const float*)d_in[1];
  const float* norm1_w  = (const float*)d_in[2];
  const float* norm2_w  = (const float*)d_in[3];
  const float* in_proj  = (const float*)d_in[4];
  const float* out_proj = (const float*)d_in[5];
  const float* ffn1_w   = (const float*)d_in[6];
  const float* ffn1_b   = (const float*)d_in[7];
  const float* ffn2_w   = (const float*)d_in[8];
  const float* ffn2_b   = (const float*)d_in[9];
  const float* hA_w1    = (const float*)d_in[10];
  const float* hA_b1    = (const float*)d_in[11];
  const float* hA_w2    = (const float*)d_in[12];
  const float* hA_b2    = (const float*)d_in[13];
  const float* hB_w1    = (const float*)d_in[14];
  const float* hB_b1    = (const float*)d_in[15];
  const float* hB_w2    = (const float*)d_in[16];
  const float* hB_b2    = (const float*)d_in[17];
  float* out = (float*)d_out;

  char* ws = (char*)d_ws;
  size_t off = 0;
  auto alloc = [&](size_t bytes) { size_t o = off; off += (bytes + 255) & ~(size_t)255; return o; };
  bf16*  Wqkv   = (bf16*)(ws + alloc(2304*768*2));
  bf16*  Wo     = (bf16*)(ws + alloc(768*768*2));
  bf16*  W2     = (bf16*)(ws + alloc(768*3072*2));
  bf16*  W1ab   = (bf16*)(ws + alloc(256*128*2));
  float* b1ab   = (float*)(ws + alloc(256*4));
  bf16*  WBp    = (bf16*)(ws + alloc(512*768*2));
  bf16*  Wc     = (bf16*)(ws + alloc((size_t)3072*LDW*2));
  bf16*  taskbf = (bf16*)(ws + alloc((size_t)NTOK*128*2));
  bf16*  XC     = (bf16*)(ws + alloc((size_t)NTOK*768*2));    // Xn1, then Ctx
  char*  QKVH   = ws + alloc(25165824);                        // Qkv(18874368)+Vt(6291456) / Hbuf
  bf16*  Qkv    = (bf16*)QKVH;
  bf16*  Vt     = (bf16*)(QKVH + 18874368);
  bf16*  Hbuf   = (bf16*)QKVH;
  float* Src2   = (float*)(ws + alloc((size_t)NTOK*768*4));
  bf16*  Aext   = (bf16*)(ws + alloc((size_t)NTOK*LDW*2));
  bf16*  HAB    = (bf16*)(ws + alloc((size_t)NTOK*256*2));
  float* P      = (float*)(ws + alloc((size_t)NTOK*512*4));

  // K0: weight prep / casts
  prep_kernel<<<dim3(1280), 256, 0, stream>>>(in_proj, out_proj, ffn1_w, ffn1_b, ffn2_w,
      hA_w1, hA_b1, hA_w2, hA_b2, hB_w1, hB_b1, hB_w2, task,
      Wqkv, Wo, W2, W1ab, b1ab, WBp, Wc, taskbf);
  // K1: x1 = rmsnorm(src, norm1_w) -> bf16
  rmsnorm_k<<<dim3(NTOK), 256, 0, stream>>>(src, norm1_w, XC, 768);
  // K2: qkv = x1 @ in_proj^T ; V block written directly to Vt
  gemm_qkv64<<<dim3(36,64), 256, 0, stream>>>(XC, Wqkv, Qkv, Vt);
  // K4: flash attention -> Ctx (reuses XC); 2 waves/block
  flash_attn<<<dim3(32,24), 128, 0, stream>>>(Qkv, Vt, XC);
  // K5: src2 = src + ctx @ out_proj^T
  gemm64<float,false,false,true><<<dim3(12,64), 256, 0, stream>>>(XC, Wo, Src2, nullptr, src, 768, 768, 768, 768);
  // K6: xn2 = rmsnorm(src2, norm2_w) -> Aext cols 0..767 (stride LDW)
  rmsnorm_k<<<dim3(NTOK), 256, 0, stream>>>(Src2, norm2_w, Aext, LDW);
  // K7: HAB = relu(task @ W1ab^T + b1ab)
  gemm64<bf16,true,true,false><<<dim3(4,64), 256, 0, stream>>>(taskbf, W1ab, HAB, b1ab, nullptr, 128, 128, 128, 256);
  // K8: P = xn2 @ WBp^T
  gemm64<float,false,false,false><<<dim3(8,64), 256, 0, stream>>>(Aext, WBp, P, nullptr, nullptr, 768, LDW, 768, 512);
  // K9: inter + g -> Aext cols 768..1343
  build_g<<<dim3(NTOK/4), 256, 0, stream>>>(HAB, P, hB_b2, Aext);
  // K10: H = relu(Aext @ Wc^T)  (128-tile, conflict-free swizzled LDS, K=1312)
  gemm_bt_sw<bf16,true,false,false><<<dim3(24,32), 256, 0, stream>>>(Aext, Wc, Hbuf, nullptr, nullptr, 1312, LDW, LDW, 3072);
  // K11: out = src2 + H @ ffn2_w^T + ffn2_b
  gemm64<float,false,true,true><<<dim3(12,64), 256, 0, stream>>>(Hbuf, W2, out, ffn2_b, Src2, 3072, 3072, 3072, 768);
}